// Round 6
// baseline (244.741 us; speedup 1.0000x reference)
//
#include <hip/hip_runtime.h>

typedef __attribute__((ext_vector_type(8))) _Float16 half8;
typedef __attribute__((ext_vector_type(4))) float floatx4;

// async global->LDS DMA, 16B per lane; lds must be wave-uniform base (+lane*16 implicit)
__device__ inline void gld16(const _Float16* g, _Float16* lds) {
  __builtin_amdgcn_global_load_lds(
      (const __attribute__((address_space(1))) unsigned int*)g,
      (__attribute__((address_space(3))) unsigned int*)lds, 16, 0, 0);
}

// ---------------- kW: fp32 -> fp16 weight planes ----------------
__global__ __launch_bounds__(256) void kW(const float* __restrict__ w1,
                                          const float* __restrict__ w2,
                                          const float* __restrict__ w3,
                                          _Float16* __restrict__ w1f,
                                          _Float16* __restrict__ w2f,
                                          _Float16* __restrict__ w3f) {
  int i = blockIdx.x * 256 + threadIdx.x;
  if (i < 202752) w1f[i] = (_Float16)w1[i];
  else if (i < 211968) w2f[i - 202752] = (_Float16)w2[i - 202752];
  else if (i < 221184) w3f[i - 211968] = (_Float16)w3[i - 211968];
}

// ---------------- kDesc: scrambled-unfold descriptors -> desc [12544, 2112] fp16 ----
// tap(k1,k2) at (h',w') = x[row=(k2*56+h')/3+k1-1, col=w'+(k2*56+h')%3-1], zero-pad.
// fp16 xb (max is monotone: round-then-max == max-then-round), ~19 KB LDS.
__global__ __launch_bounds__(320) void kDesc(const float* __restrict__ x,
                                             _Float16* __restrict__ descF) {
  int bid = blockIdx.x;
  int g = bid & 15;
  int h = (bid >> 4) % 56;
  int b = bid / 896;
  __shared__ _Float16 xb[144 * 58];     // [(kk*16+ch)*58 + wc], kk=k2*3+k1
  __shared__ int tOff[4][132];
  __shared__ int tDg[132];

  int t = threadIdx.x;
  if (t < 132) {
    int dl = t;
    int o0, o1, o2, o3, dg;
    if (dl < 36) {                       // x1: max over 4 sub-channels
      int a3 = dl / 9, rem = dl % 9, k1 = rem / 3, k2 = rem % 3;
      int j2k = (k2 * 56 + h) % 3;
      int base = (k2 * 3 + k1) * 16;
      o0 = (base + a3) * 58 + j2k;
      o1 = (base + 4 + a3) * 58 + j2k;
      o2 = (base + 8 + a3) * 58 + j2k;
      o3 = (base + 12 + a3) * 58 + j2k;
      dg = g * 36 + dl;
    } else if (dl < 84) {                // x2: max over k1
      int u = dl - 36, gc = u / 3, k2 = u % 3;
      int j2k = (k2 * 56 + h) % 3;
      o0 = ((k2 * 3 + 0) * 16 + gc) * 58 + j2k;
      o1 = ((k2 * 3 + 1) * 16 + gc) * 58 + j2k;
      o2 = ((k2 * 3 + 2) * 16 + gc) * 58 + j2k;
      o3 = o0;
      dg = 576 + g * 48 + u;
    } else {                             // x3: max over k2
      int u = dl - 84, gc = u / 3, k1 = u % 3;
      o0 = ((0 * 3 + k1) * 16 + gc) * 58 + ((0 * 56 + h) % 3);
      o1 = ((1 * 3 + k1) * 16 + gc) * 58 + ((1 * 56 + h) % 3);
      o2 = ((2 * 3 + k1) * 16 + gc) * 58 + ((2 * 56 + h) % 3);
      o3 = o0;
      dg = 1344 + g * 48 + u;
    }
    tOff[0][dl] = o0; tOff[1][dl] = o1; tOff[2][dl] = o2; tOff[3][dl] = o3;
    tDg[dl] = dg;
  }

  // fill xb: 144 rows x 58 cols, batched loads for MLP
  {
    int wc = t & 63;
    int r0 = t >> 6;                     // 0..4
    int wr = wc - 1;
    bool wok = (wc < 58) & (wr >= 0) & (wr < 56);
    const long xb0 = ((long)b * 256 + g * 16) * 3136;
#pragma unroll
    for (int ch_ = 0; ch_ < 3; ++ch_) {
      const int nI = (ch_ < 2) ? 10 : 9;
      float vals[10];
#pragma unroll
      for (int i = 0; i < nI; ++i) {
        int row = r0 + (ch_ * 10 + i) * 5;
        int kk = row >> 4, ch = row & 15;
        int k2 = kk / 3, k1 = kk - 3 * k2;
        int gr = (k2 * 56 + h) / 3 + k1 - 1;
        float v = 0.f;
        if (wok && row < 144 && gr >= 0 && gr < 56)
          v = x[xb0 + ch * 3136 + (long)gr * 56 + wr];
        vals[i] = v;
      }
#pragma unroll
      for (int i = 0; i < nI; ++i) {
        int row = r0 + (ch_ * 10 + i) * 5;
        if (row < 144 && wc < 58) xb[row * 58 + wc] = (_Float16)vals[i];
      }
    }
  }
  __syncthreads();

  if (t < 264) {
    int p0 = (t >= 132) ? 1 : 0;
    int dl = t - p0 * 132;
    int o0 = tOff[0][dl], o1 = tOff[1][dl], o2 = tOff[2][dl], o3 = tOff[3][dl];
    long dbase = ((long)(b * 56 + h)) * 56 * 2112 + tDg[dl];
#pragma unroll
    for (int i = 0; i < 28; ++i) {
      int p = p0 + i * 2;
      _Float16 v0 = xb[o0 + p], v1 = xb[o1 + p], v2 = xb[o2 + p], v3 = xb[o3 + p];
      _Float16 va = v0 > v1 ? v0 : v1;
      _Float16 vb = v2 > v3 ? v2 : v3;
      descF[dbase + (long)p * 2112] = va > vb ? va : vb;
    }
  }
}

// ---------------- kGemm1: split-K partial GEMM, LDS-staged via global_load_lds ----------
// grid = 196 Mtiles x 11 K-chunks = 2156 blocks; 256 threads; M=64, N=96, K-chunk=192, BK=32.
__global__ __launch_bounds__(256) void kGemm1(
    const _Float16* __restrict__ descF, const _Float16* __restrict__ w1f,
    _Float16* __restrict__ pacc) {
  __shared__ _Float16 Ab[2][64 * 32];   // [row*32 + c*8]
  __shared__ _Float16 Bb[2][96 * 32];   // [n*32 + c*8]
  const int t = threadIdx.x;
  const int wv = t >> 6, lane = t & 63, quad = lane >> 4, lr = lane & 15;
  const int mt = blockIdx.x / 11, ck = blockIdx.x % 11;
  const long mblk = (long)mt * 64;

  const long agbase = (mblk + (t >> 2)) * 2112 + ck * 192 + (t & 3) * 8;
  const long bg0 = (long)(t >> 2) * 2112 + ck * 192 + (t & 3) * 8;
  const long bg1 = (long)((256 + t) >> 2) * 2112 + ck * 192 + (t & 3) * 8;
  const int wslot = (t >> 6) * 512;     // wave-uniform LDS base (halves)

  floatx4 acc[6];
#pragma unroll
  for (int j = 0; j < 6; ++j) acc[j] = {0.f, 0.f, 0.f, 0.f};

  gld16(descF + agbase, &Ab[0][wslot]);
  gld16(w1f + bg0, &Bb[0][wslot]);
  if (t < 128) gld16(w1f + bg1, &Bb[0][2048 + wslot]);

  int buf = 0;
  for (int kt = 0; kt < 6; ++kt) {
    __syncthreads();
    if (kt < 5) {
      int off = (kt + 1) * 32;
      gld16(descF + agbase + off, &Ab[buf ^ 1][wslot]);
      gld16(w1f + bg0 + off, &Bb[buf ^ 1][wslot]);
      if (t < 128) gld16(w1f + bg1 + off, &Bb[buf ^ 1][2048 + wslot]);
    }
    half8 af = *(const half8*)(&Ab[buf][(wv * 16 + lr) * 32 + quad * 8]);
#pragma unroll
    for (int j = 0; j < 6; ++j) {
      half8 bf = *(const half8*)(&Bb[buf][(j * 16 + lr) * 32 + quad * 8]);
      acc[j] = __builtin_amdgcn_mfma_f32_16x16x32_f16(af, bf, acc[j], 0, 0, 0);
    }
    buf ^= 1;
  }

  _Float16* pp = pacc + (long)(ck * 196 + mt) * 6144;
#pragma unroll
  for (int j = 0; j < 6; ++j)
#pragma unroll
    for (int r = 0; r < 4; ++r)
      pp[(wv * 16 + quad * 4 + r) * 96 + j * 16 + lr] = (_Float16)acc[j][r];
}

// ---------------- kGemm2: sum partials -> BN/ReLU -> GEMM2 (w2,w3) -> softmax -> wt fp16 ----
__global__ __launch_bounds__(256) void kGemm2(
    const _Float16* __restrict__ pacc,
    const _Float16* __restrict__ w2f, const _Float16* __restrict__ w3f,
    const float* __restrict__ gamma, const float* __restrict__ beta,
    const float* __restrict__ mean, const float* __restrict__ var,
    const float* __restrict__ b2, const float* __restrict__ b3,
    _Float16* __restrict__ wtg) {
  __shared__ __align__(16) char smem[49152];
  float* ysum = (float*)smem;                              // 6144 f32
  _Float16* ytF = (_Float16*)(smem + 24576);               // 64*104 fp16
  float* wal = (float*)smem;                               // phase3
  float* wbl = (float*)(smem + 24576);                     // phase3
  __shared__ float invv[96], biasv[96];

  const int t = threadIdx.x;
  const int wv = t >> 6, lane = t & 63, quad = lane >> 4, lr = lane & 15;
  const int mt = blockIdx.x;
  const long mblk = (long)mt * 64;

  if (t < 96) {
    float iv = gamma[t] * rsqrtf(var[t] + 1e-5f);
    invv[t] = iv; biasv[t] = beta[t] - mean[t] * iv;
  }

  {
    const _Float16* pb = pacc + (long)mt * 6144;
#pragma unroll
    for (int i = 0; i < 24; ++i) {
      int idx = t + i * 256;
      float s = 0.f;
#pragma unroll
      for (int ckk = 0; ckk < 11; ++ckk)
        s += (float)pb[(long)ckk * 196 * 6144 + idx];
      ysum[idx] = s;
    }
  }
  __syncthreads();

#pragma unroll
  for (int i = 0; i < 24; ++i) {
    int idx = t + i * 256;
    int m = idx / 96, n = idx - m * 96;
    float y = fmaxf(ysum[idx] * invv[n] + biasv[n], 0.f);
    ytF[m * 104 + n] = (_Float16)y;
  }
  __syncthreads();

  floatx4 acc2a[6], acc2b[6];
#pragma unroll
  for (int j = 0; j < 6; ++j) { acc2a[j] = {0.f,0.f,0.f,0.f}; acc2b[j] = {0.f,0.f,0.f,0.f}; }
#pragma unroll
  for (int ks = 0; ks < 3; ++ks) {
    half8 af = *(const half8*)(ytF + (wv * 16 + lr) * 104 + ks * 32 + quad * 8);
#pragma unroll
    for (int j = 0; j < 6; ++j) {
      int wo = (j * 16 + lr) * 96 + ks * 32 + quad * 8;
      half8 b2v = *(const half8*)(w2f + wo);
      half8 b3v = *(const half8*)(w3f + wo);
      acc2a[j] = __builtin_amdgcn_mfma_f32_16x16x32_f16(af, b2v, acc2a[j], 0, 0, 0);
      acc2b[j] = __builtin_amdgcn_mfma_f32_16x16x32_f16(af, b3v, acc2b[j], 0, 0, 0);
    }
  }
  __syncthreads();

#pragma unroll
  for (int j = 0; j < 6; ++j) {
    int n = j * 16 + lr;
    float bb2 = b2[n], bb3 = b3[n];
#pragma unroll
    for (int r = 0; r < 4; ++r) {
      int m = wv * 16 + quad * 4 + r;
      wal[m * 96 + n] = acc2a[j][r] + bb2;
      wbl[m * 96 + n] = acc2b[j][r] + bb3;
    }
  }
  __syncthreads();

  for (int it = 0; it < 16; ++it) {
    int u = t + it * 256;
    int m = u >> 6, rest = u & 63;
    int g = rest >> 2, ns = rest & 3;
    int ns1 = ns >> 1, ns2 = ns & 1;
    float la[3], lb[3];
#pragma unroll
    for (int k = 0; k < 3; ++k) {
      la[k] = wal[m * 96 + (g * 3 + k) * 2 + ns1];
      lb[k] = wbl[m * 96 + (g * 3 + k) * 2 + ns2];
    }
    float lg[9], mx = -1e30f;
#pragma unroll
    for (int k1 = 0; k1 < 3; ++k1)
#pragma unroll
      for (int k2 = 0; k2 < 3; ++k2) {
        float v = la[k1] * lb[k2];
        lg[k1 * 3 + k2] = v;
        mx = v > mx ? v : mx;
      }
    float s = 0.f;
#pragma unroll
    for (int k = 0; k < 9; ++k) { lg[k] = __expf(lg[k] - mx); s += lg[k]; }
    float sc = 1.f / (9.f * s);
    _Float16* dst = wtg + (mblk + m) * 576 + g * 36 + ns * 9;
#pragma unroll
    for (int k = 0; k < 9; ++k) dst[k] = (_Float16)(lg[k] * sc);
  }
}

// ---------------- kApply: x + wt -> out ----------
// block = (b, h', wh(2), g(16)): 7168 blocks, 256 threads; 16 channels, 28 w-positions.
// Each thread owns (cl,p) and computes all 4 ns outputs: 9 xr reads shared across ns.
// LDS ~20 KB -> 8 blocks/CU.
__global__ __launch_bounds__(256) void kApply(const float* __restrict__ x,
                                              const _Float16* __restrict__ wt,
                                              float* __restrict__ out) {
  int bid = blockIdx.x;
  int g = bid & 15;
  int wh = (bid >> 4) & 1;
  int h = (bid >> 5) % 56;
  int b = bid / 1792;
  int wbase = wh * 28, cbase = g * 16;

  __shared__ _Float16 xr[9 * 16 * 30];       // [(k2*3+k1)*480 + cl*30 + wc]
  __shared__ __align__(16) float wtb[28 * 36]; // [p*36 + (k1*3+k2)*4 + ns]
  __shared__ float ob[32 * 57];              // [(cl*2+ns1)*57 + p*2+ns2]

  int t = threadIdx.x;

  // fill xr: 144 rows x 30 cols; fully-batched loads (18/thread in flight)
  {
    int wc = t & 31;
    int r0 = t >> 5;                    // 0..7
    int wr = wbase + wc - 1;
    bool wok = (wc < 30) & (wr >= 0) & (wr < 56);
    const long xb0 = ((long)b * 256 + cbase) * 3136;
    float vals[18];
#pragma unroll
    for (int i = 0; i < 18; ++i) {
      int row = r0 + i * 8;             // 0..143
      int kk = row >> 4, cl = row & 15;
      int k2 = kk / 3, k1 = kk - 3 * k2;
      int gr = (k2 * 56 + h) / 3 + k1 - 1;
      float v = 0.f;
      if (wok && gr >= 0 && gr < 56)
        v = x[xb0 + (long)cl * 3136 + gr * 56 + wr];
      vals[i] = v;
    }
#pragma unroll
    for (int i = 0; i < 18; ++i) {
      int row = r0 + i * 8;
      if (wc < 30) xr[row * 30 + wc] = (_Float16)vals[i];
    }
  }
  // wt -> wtb: wtb[p*36 + kk*4 + ns] = wt[(m0+p)*576 + g*36 + ns*9 + kk]
  {
    long m0 = ((long)(b * 56 + h)) * 56 + wbase;
    float vals[4];
#pragma unroll
    for (int i = 0; i < 4; ++i) {
      int idx = t + i * 256;
      if (idx < 1008) {
        int p = idx / 36, r36 = idx - p * 36;
        int kk = r36 >> 2, ns = r36 & 3;
        vals[i] = (float)wt[(m0 + p) * 576 + g * 36 + ns * 9 + kk];
      }
    }
#pragma unroll
    for (int i = 0; i < 4; ++i) {
      int idx = t + i * 256;
      if (idx < 1008) wtb[idx] = vals[i];
    }
  }
  __syncthreads();

  // compute: thread owns (cl, p); 4 ns accumulators; float4 weight reads
  {
    int j2r[3];
#pragma unroll
    for (int k2 = 0; k2 < 3; ++k2) j2r[k2] = (k2 * 56 + h) % 3;
#pragma unroll
    for (int i = 0; i < 2; ++i) {
      int idx = i * 256 + t;
      int cl = idx & 15;
      int p = idx >> 4;                 // 0..31
      if (p < 28) {
        float a0 = 0.f, a1 = 0.f, a2 = 0.f, a3 = 0.f;
#pragma unroll
        for (int k1 = 0; k1 < 3; ++k1)
#pragma unroll
          for (int k2 = 0; k2 < 3; ++k2) {
            float xv = (float)xr[(k2 * 3 + k1) * 480 + cl * 30 + p + j2r[k2]];
            float4 wv = *(const float4*)&wtb[p * 36 + (k1 * 3 + k2) * 4];
            a0 += xv * wv.x; a1 += xv * wv.y; a2 += xv * wv.z; a3 += xv * wv.w;
          }
        int ob0 = cl * 114 + p * 2;
        ob[ob0] = a0;
        ob[ob0 + 1] = a1;
        ob[ob0 + 57] = a2;
        ob[ob0 + 58] = a3;
      }
    }
  }
  __syncthreads();

  // writeout: 32 rows x 56 cols, coalesced
  {
    int wo = t & 63;
    int r0 = t >> 6;                    // 0..3
    const long obase = (((long)b * 256 + cbase) * 112 + 2 * h) * 112 + wh * 56;
#pragma unroll
    for (int i = 0; i < 8; ++i) {
      int row = r0 + i * 4;             // 0..31
      if (wo < 56) {
        int cli = row >> 1, n1 = row & 1;
        out[obase + cli * 12544 + n1 * 112 + wo] = ob[row * 57 + wo];
      }
    }
  }
}

extern "C" void kernel_launch(void* const* d_in, const int* in_sizes, int n_in,
                              void* d_out, int out_size, void* d_ws, size_t ws_size,
                              hipStream_t stream) {
  const float* x = (const float*)d_in[0];
  const float* w1 = (const float*)d_in[1];
  const float* gamma = (const float*)d_in[2];
  const float* beta = (const float*)d_in[3];
  const float* mean = (const float*)d_in[4];
  const float* var = (const float*)d_in[5];
  const float* w2 = (const float*)d_in[6];
  const float* b2 = (const float*)d_in[7];
  const float* w3 = (const float*)d_in[8];
  const float* b3 = (const float*)d_in[9];
  float* out = (float*)d_out;

  // workspace layout (bytes), total ~94.4 MB:
  //   w1f fp16:   [0, 405504)
  //   w2f fp16:   [405504, 423936)
  //   w3f fp16:   [423936, 442368)
  //   wtg fp16:   [442368, 14893056)
  //   descF fp16: [14893056, 67878912)
  //   pacc fp16:  [67878912, 94371840)   (11 split-K slices)
  _Float16* w1f = (_Float16*)d_ws;
  _Float16* w2f = w1f + 202752;
  _Float16* w3f = w2f + 9216;
  _Float16* wtg = (_Float16*)((char*)d_ws + 442368);
  _Float16* descF = (_Float16*)((char*)d_ws + 14893056);
  _Float16* pacc = (_Float16*)((char*)d_ws + 67878912);

  hipLaunchKernelGGL(kW, dim3(864), dim3(256), 0, stream, w1, w2, w3, w1f, w2f, w3f);
  hipLaunchKernelGGL(kDesc, dim3(3584), dim3(320), 0, stream, x, descF);
  hipLaunchKernelGGL(kGemm1, dim3(2156), dim3(256), 0, stream, descF, w1f, pacc);
  hipLaunchKernelGGL(kGemm2, dim3(196), dim3(256), 0, stream,
                     pacc, w2f, w3f, gamma, beta, mean, var, b2, b3, wtg);
  hipLaunchKernelGGL(kApply, dim3(7168), dim3(256), 0, stream, x, wtg, out);
}

// Round 8
// 197.819 us; speedup vs baseline: 1.2372x; 1.2372x over previous
//
#include <hip/hip_runtime.h>

typedef __attribute__((ext_vector_type(8))) _Float16 half8;
typedef __attribute__((ext_vector_type(4))) _Float16 half4;
typedef __attribute__((ext_vector_type(4))) float floatx4;

// async global->LDS DMA, 16B per lane; lds must be wave-uniform base (+lane*16 implicit)
__device__ inline void gld16(const _Float16* g, _Float16* lds) {
  __builtin_amdgcn_global_load_lds(
      (const __attribute__((address_space(1))) unsigned int*)g,
      (__attribute__((address_space(3))) unsigned int*)lds, 16, 0, 0);
}

// ---------------- kW: fp32 -> fp16 weight planes ----------------
__global__ __launch_bounds__(256) void kW(const float* __restrict__ w1,
                                          const float* __restrict__ w2,
                                          const float* __restrict__ w3,
                                          _Float16* __restrict__ w1f,
                                          _Float16* __restrict__ w2f,
                                          _Float16* __restrict__ w3f) {
  int i = blockIdx.x * 256 + threadIdx.x;
  if (i < 202752) w1f[i] = (_Float16)w1[i];
  else if (i < 211968) w2f[i - 202752] = (_Float16)w2[i - 202752];
  else if (i < 221184) w3f[i - 211968] = (_Float16)w3[i - 211968];
}

// ---------------- kDesc: scrambled-unfold descriptors -> desc [12544, 2112] fp16 ----
// tap(k1,k2) at (h',w') = x[row=(k2*56+h')/3+k1-1, col=w'+(k2*56+h')%3-1], zero-pad.
__global__ __launch_bounds__(320) void kDesc(const float* __restrict__ x,
                                             _Float16* __restrict__ descF) {
  int bid = blockIdx.x;
  int g = bid & 15;
  int h = (bid >> 4) % 56;
  int b = bid / 896;
  __shared__ _Float16 xb[144 * 58];     // [(kk*16+ch)*58 + wc], kk=k2*3+k1
  __shared__ int tOff[4][132];
  __shared__ int tDg[132];

  int t = threadIdx.x;
  if (t < 132) {
    int dl = t;
    int o0, o1, o2, o3, dg;
    if (dl < 36) {                       // x1: max over 4 sub-channels
      int a3 = dl / 9, rem = dl % 9, k1 = rem / 3, k2 = rem % 3;
      int j2k = (k2 * 56 + h) % 3;
      int base = (k2 * 3 + k1) * 16;
      o0 = (base + a3) * 58 + j2k;
      o1 = (base + 4 + a3) * 58 + j2k;
      o2 = (base + 8 + a3) * 58 + j2k;
      o3 = (base + 12 + a3) * 58 + j2k;
      dg = g * 36 + dl;
    } else if (dl < 84) {                // x2: max over k1
      int u = dl - 36, gc = u / 3, k2 = u % 3;
      int j2k = (k2 * 56 + h) % 3;
      o0 = ((k2 * 3 + 0) * 16 + gc) * 58 + j2k;
      o1 = ((k2 * 3 + 1) * 16 + gc) * 58 + j2k;
      o2 = ((k2 * 3 + 2) * 16 + gc) * 58 + j2k;
      o3 = o0;
      dg = 576 + g * 48 + u;
    } else {                             // x3: max over k2
      int u = dl - 84, gc = u / 3, k1 = u % 3;
      o0 = ((0 * 3 + k1) * 16 + gc) * 58 + ((0 * 56 + h) % 3);
      o1 = ((1 * 3 + k1) * 16 + gc) * 58 + ((1 * 56 + h) % 3);
      o2 = ((2 * 3 + k1) * 16 + gc) * 58 + ((2 * 56 + h) % 3);
      o3 = o0;
      dg = 1344 + g * 48 + u;
    }
    tOff[0][dl] = o0; tOff[1][dl] = o1; tOff[2][dl] = o2; tOff[3][dl] = o3;
    tDg[dl] = dg;
  }

  // fill xb: 144 rows x 58 cols, batched loads for MLP
  {
    int wc = t & 63;
    int r0 = t >> 6;                     // 0..4
    int wr = wc - 1;
    bool wok = (wc < 58) & (wr >= 0) & (wr < 56);
    const long xb0 = ((long)b * 256 + g * 16) * 3136;
#pragma unroll
    for (int ch_ = 0; ch_ < 3; ++ch_) {
      const int nI = (ch_ < 2) ? 10 : 9;
      float vals[10];
#pragma unroll
      for (int i = 0; i < nI; ++i) {
        int row = r0 + (ch_ * 10 + i) * 5;
        int kk = row >> 4, ch = row & 15;
        int k2 = kk / 3, k1 = kk - 3 * k2;
        int gr = (k2 * 56 + h) / 3 + k1 - 1;
        float v = 0.f;
        if (wok && row < 144 && gr >= 0 && gr < 56)
          v = x[xb0 + ch * 3136 + (long)gr * 56 + wr];
        vals[i] = v;
      }
#pragma unroll
      for (int i = 0; i < nI; ++i) {
        int row = r0 + (ch_ * 10 + i) * 5;
        if (row < 144 && wc < 58) xb[row * 58 + wc] = (_Float16)vals[i];
      }
    }
  }
  __syncthreads();

  if (t < 264) {
    int p0 = (t >= 132) ? 1 : 0;
    int dl = t - p0 * 132;
    int o0 = tOff[0][dl], o1 = tOff[1][dl], o2 = tOff[2][dl], o3 = tOff[3][dl];
    long dbase = ((long)(b * 56 + h)) * 56 * 2112 + tDg[dl];
#pragma unroll
    for (int i = 0; i < 28; ++i) {
      int p = p0 + i * 2;
      _Float16 v0 = xb[o0 + p], v1 = xb[o1 + p], v2 = xb[o2 + p], v3 = xb[o3 + p];
      _Float16 va = v0 > v1 ? v0 : v1;
      _Float16 vb = v2 > v3 ? v2 : v3;
      descF[dbase + (long)p * 2112] = va > vb ? va : vb;
    }
  }
}

// ---------------- kGemm1: split-K partial GEMM, LDS-staged via global_load_lds ----------
// grid = 196 Mtiles x 11 K-chunks = 2156 blocks; 256 threads; M=64, N=96, K-chunk=192, BK=32.
__global__ __launch_bounds__(256) void kGemm1(
    const _Float16* __restrict__ descF, const _Float16* __restrict__ w1f,
    _Float16* __restrict__ pacc) {
  __shared__ _Float16 Ab[2][64 * 32];   // [row*32 + c*8]
  __shared__ _Float16 Bb[2][96 * 32];   // [n*32 + c*8]
  const int t = threadIdx.x;
  const int wv = t >> 6, lane = t & 63, quad = lane >> 4, lr = lane & 15;
  const int mt = blockIdx.x / 11, ck = blockIdx.x % 11;
  const long mblk = (long)mt * 64;

  const long agbase = (mblk + (t >> 2)) * 2112 + ck * 192 + (t & 3) * 8;
  const long bg0 = (long)(t >> 2) * 2112 + ck * 192 + (t & 3) * 8;
  const long bg1 = (long)((256 + t) >> 2) * 2112 + ck * 192 + (t & 3) * 8;
  const int wslot = (t >> 6) * 512;     // wave-uniform LDS base (halves)

  floatx4 acc[6];
#pragma unroll
  for (int j = 0; j < 6; ++j) acc[j] = {0.f, 0.f, 0.f, 0.f};

  gld16(descF + agbase, &Ab[0][wslot]);
  gld16(w1f + bg0, &Bb[0][wslot]);
  if (t < 128) gld16(w1f + bg1, &Bb[0][2048 + wslot]);

  int buf = 0;
  for (int kt = 0; kt < 6; ++kt) {
    __syncthreads();
    if (kt < 5) {
      int off = (kt + 1) * 32;
      gld16(descF + agbase + off, &Ab[buf ^ 1][wslot]);
      gld16(w1f + bg0 + off, &Bb[buf ^ 1][wslot]);
      if (t < 128) gld16(w1f + bg1 + off, &Bb[buf ^ 1][2048 + wslot]);
    }
    half8 af = *(const half8*)(&Ab[buf][(wv * 16 + lr) * 32 + quad * 8]);
#pragma unroll
    for (int j = 0; j < 6; ++j) {
      half8 bf = *(const half8*)(&Bb[buf][(j * 16 + lr) * 32 + quad * 8]);
      acc[j] = __builtin_amdgcn_mfma_f32_16x16x32_f16(af, bf, acc[j], 0, 0, 0);
    }
    buf ^= 1;
  }

  _Float16* pp = pacc + (long)(ck * 196 + mt) * 6144;
#pragma unroll
  for (int j = 0; j < 6; ++j)
#pragma unroll
    for (int r = 0; r < 4; ++r)
      pp[(wv * 16 + quad * 4 + r) * 96 + j * 16 + lr] = (_Float16)acc[j][r];
}

// ---------------- kRed: sum 11 split-K partials + BN + ReLU -> y fp16 [12544, 96] -------
// 1176 blocks x 256 threads x 4 elements = 1,204,224 = 196*6144 exactly.
__global__ __launch_bounds__(256) void kRed(
    const _Float16* __restrict__ pacc,
    const float* __restrict__ gamma, const float* __restrict__ beta,
    const float* __restrict__ mean, const float* __restrict__ var,
    _Float16* __restrict__ yred) {
  __shared__ float invv[96], biasv[96];
  int t = threadIdx.x;
  if (t < 96) {
    float iv = gamma[t] * rsqrtf(var[t] + 1e-5f);
    invv[t] = iv; biasv[t] = beta[t] - mean[t] * iv;
  }
  __syncthreads();
  long base = (long)blockIdx.x * 1024 + t * 4;
  float s0 = 0.f, s1 = 0.f, s2 = 0.f, s3 = 0.f;
#pragma unroll
  for (int ck = 0; ck < 11; ++ck) {
    half4 v = *(const half4*)(pacc + (long)ck * 1204224 + base);
    s0 += (float)v.x; s1 += (float)v.y; s2 += (float)v.z; s3 += (float)v.w;
  }
  int n0 = (int)(base % 96);   // 4-aligned, 96%4==0 -> no row crossing
  half4 o;
  o.x = (_Float16)fmaxf(s0 * invv[n0 + 0] + biasv[n0 + 0], 0.f);
  o.y = (_Float16)fmaxf(s1 * invv[n0 + 1] + biasv[n0 + 1], 0.f);
  o.z = (_Float16)fmaxf(s2 * invv[n0 + 2] + biasv[n0 + 2], 0.f);
  o.w = (_Float16)fmaxf(s3 * invv[n0 + 3] + biasv[n0 + 3], 0.f);
  *(half4*)(yred + base) = o;
}

// ---------------- kGemm2: y tile -> GEMM2 (w2,w3) -> softmax -> wt fp16 ----
__global__ __launch_bounds__(256) void kGemm2(
    const _Float16* __restrict__ yred,
    const _Float16* __restrict__ w2f, const _Float16* __restrict__ w3f,
    const float* __restrict__ b2, const float* __restrict__ b3,
    _Float16* __restrict__ wtg) {
  __shared__ __align__(16) char smem[49152];
  _Float16* ytF = (_Float16*)smem;        // [0, 13312): 64*104 fp16 (dead after MFMA loop)
  float* wal = (float*)smem;              // [0, 24576): 64*96 f32  (after ytF dead)
  float* wbl = wal + 6144;                // [24576, 49152): 64*96 f32

  const int t = threadIdx.x;
  const int wv = t >> 6, lane = t & 63, quad = lane >> 4, lr = lane & 15;
  const int mt = blockIdx.x;
  const long mblk = (long)mt * 64;

  // load y tile (coalesced fp16) -> ytF [64][104]
  {
    const _Float16* yb = yred + mblk * 96;
#pragma unroll
    for (int i = 0; i < 24; ++i) {
      int idx = t + i * 256;
      int m = idx / 96, n = idx - m * 96;
      ytF[m * 104 + n] = yb[idx];
    }
  }
  __syncthreads();

  floatx4 acc2a[6], acc2b[6];
#pragma unroll
  for (int j = 0; j < 6; ++j) { acc2a[j] = {0.f,0.f,0.f,0.f}; acc2b[j] = {0.f,0.f,0.f,0.f}; }
#pragma unroll
  for (int ks = 0; ks < 3; ++ks) {
    half8 af = *(const half8*)(ytF + (wv * 16 + lr) * 104 + ks * 32 + quad * 8);
#pragma unroll
    for (int j = 0; j < 6; ++j) {
      int wo = (j * 16 + lr) * 96 + ks * 32 + quad * 8;
      half8 b2v = *(const half8*)(w2f + wo);
      half8 b3v = *(const half8*)(w3f + wo);
      acc2a[j] = __builtin_amdgcn_mfma_f32_16x16x32_f16(af, b2v, acc2a[j], 0, 0, 0);
      acc2b[j] = __builtin_amdgcn_mfma_f32_16x16x32_f16(af, b3v, acc2b[j], 0, 0, 0);
    }
  }
  __syncthreads();   // ytF dead; smem becomes wal/wbl

#pragma unroll
  for (int j = 0; j < 6; ++j) {
    int n = j * 16 + lr;
    float bb2 = b2[n], bb3 = b3[n];
#pragma unroll
    for (int r = 0; r < 4; ++r) {
      int m = wv * 16 + quad * 4 + r;
      wal[m * 96 + n] = acc2a[j][r] + bb2;
      wbl[m * 96 + n] = acc2b[j][r] + bb3;
    }
  }
  __syncthreads();

  for (int it = 0; it < 16; ++it) {
    int u = t + it * 256;
    int m = u >> 6, rest = u & 63;
    int g = rest >> 2, ns = rest & 3;
    int ns1 = ns >> 1, ns2 = ns & 1;
    float la[3], lb[3];
#pragma unroll
    for (int k = 0; k < 3; ++k) {
      la[k] = wal[m * 96 + (g * 3 + k) * 2 + ns1];
      lb[k] = wbl[m * 96 + (g * 3 + k) * 2 + ns2];
    }
    float lg[9], mx = -1e30f;
#pragma unroll
    for (int k1 = 0; k1 < 3; ++k1)
#pragma unroll
      for (int k2 = 0; k2 < 3; ++k2) {
        float v = la[k1] * lb[k2];
        lg[k1 * 3 + k2] = v;
        mx = v > mx ? v : mx;
      }
    float s = 0.f;
#pragma unroll
    for (int k = 0; k < 9; ++k) { lg[k] = __expf(lg[k] - mx); s += lg[k]; }
    float sc = 1.f / (9.f * s);
    _Float16* dst = wtg + (mblk + m) * 576 + g * 36 + ns * 9;
#pragma unroll
    for (int k = 0; k < 9; ++k) dst[k] = (_Float16)(lg[k] * sc);
  }
}

// ---------------- kApply: x + wt -> out ----------
// block = (b, h', wh(2), g(16)): 7168 blocks, 256 threads; 16 channels, 28 w-positions.
__global__ __launch_bounds__(256) void kApply(const float* __restrict__ x,
                                              const _Float16* __restrict__ wt,
                                              float* __restrict__ out) {
  int bid = blockIdx.x;
  int g = bid & 15;
  int wh = (bid >> 4) & 1;
  int h = (bid >> 5) % 56;
  int b = bid / 1792;
  int wbase = wh * 28, cbase = g * 16;

  __shared__ _Float16 xr[9 * 16 * 30];       // [(k2*3+k1)*480 + cl*30 + wc]
  __shared__ __align__(16) float wtb[28 * 36]; // [p*36 + (k1*3+k2)*4 + ns]
  __shared__ float ob[32 * 57];              // [(cl*2+ns1)*57 + p*2+ns2]

  int t = threadIdx.x;

  // fill xr: 144 rows x 30 cols; fully-batched loads
  {
    int wc = t & 31;
    int r0 = t >> 5;                    // 0..7
    int wr = wbase + wc - 1;
    bool wok = (wc < 30) & (wr >= 0) & (wr < 56);
    const long xb0 = ((long)b * 256 + cbase) * 3136;
    float vals[18];
#pragma unroll
    for (int i = 0; i < 18; ++i) {
      int row = r0 + i * 8;             // 0..143
      int kk = row >> 4, cl = row & 15;
      int k2 = kk / 3, k1 = kk - 3 * k2;
      int gr = (k2 * 56 + h) / 3 + k1 - 1;
      float v = 0.f;
      if (wok && gr >= 0 && gr < 56)
        v = x[xb0 + (long)cl * 3136 + gr * 56 + wr];
      vals[i] = v;
    }
#pragma unroll
    for (int i = 0; i < 18; ++i) {
      int row = r0 + i * 8;
      if (wc < 30) xr[row * 30 + wc] = (_Float16)vals[i];
    }
  }
  // wt -> wtb: wtb[p*36 + kk*4 + ns] = wt[(m0+p)*576 + g*36 + ns*9 + kk]
  {
    long m0 = ((long)(b * 56 + h)) * 56 + wbase;
    float vals[4];
#pragma unroll
    for (int i = 0; i < 4; ++i) {
      int idx = t + i * 256;
      if (idx < 1008) {
        int p = idx / 36, r36 = idx - p * 36;
        int kk = r36 >> 2, ns = r36 & 3;
        vals[i] = (float)wt[(m0 + p) * 576 + g * 36 + ns * 9 + kk];
      }
    }
#pragma unroll
    for (int i = 0; i < 4; ++i) {
      int idx = t + i * 256;
      if (idx < 1008) wtb[idx] = vals[i];
    }
  }
  __syncthreads();

  // compute: thread owns (cl, p); 4 ns accumulators; float4 weight reads
  {
    int j2r[3];
#pragma unroll
    for (int k2 = 0; k2 < 3; ++k2) j2r[k2] = (k2 * 56 + h) % 3;
#pragma unroll
    for (int i = 0; i < 2; ++i) {
      int idx = i * 256 + t;
      int cl = idx & 15;
      int p = idx >> 4;                 // 0..31
      if (p < 28) {
        float a0 = 0.f, a1 = 0.f, a2 = 0.f, a3 = 0.f;
#pragma unroll
        for (int k1 = 0; k1 < 3; ++k1)
#pragma unroll
          for (int k2 = 0; k2 < 3; ++k2) {
            float xv = (float)xr[(k2 * 3 + k1) * 480 + cl * 30 + p + j2r[k2]];
            float4 wv = *(const float4*)&wtb[p * 36 + (k1 * 3 + k2) * 4];
            a0 += xv * wv.x; a1 += xv * wv.y; a2 += xv * wv.z; a3 += xv * wv.w;
          }
        int ob0 = cl * 114 + p * 2;
        ob[ob0] = a0;
        ob[ob0 + 1] = a1;
        ob[ob0 + 57] = a2;
        ob[ob0 + 58] = a3;
      }
    }
  }
  __syncthreads();

  // writeout: 32 rows x 56 cols, coalesced
  {
    int wo = t & 63;
    int r0 = t >> 6;                    // 0..3
    const long obase = (((long)b * 256 + cbase) * 112 + 2 * h) * 112 + wh * 56;
#pragma unroll
    for (int i = 0; i < 8; ++i) {
      int row = r0 + i * 4;             // 0..31
      if (wo < 56) {
        int cli = row >> 1, n1 = row & 1;
        out[obase + cli * 12544 + n1 * 112 + wo] = ob[row * 57 + wo];
      }
    }
  }
}

extern "C" void kernel_launch(void* const* d_in, const int* in_sizes, int n_in,
                              void* d_out, int out_size, void* d_ws, size_t ws_size,
                              hipStream_t stream) {
  const float* x = (const float*)d_in[0];
  const float* w1 = (const float*)d_in[1];
  const float* gamma = (const float*)d_in[2];
  const float* beta = (const float*)d_in[3];
  const float* mean = (const float*)d_in[4];
  const float* var = (const float*)d_in[5];
  const float* w2 = (const float*)d_in[6];
  const float* b2 = (const float*)d_in[7];
  const float* w3 = (const float*)d_in[8];
  const float* b3 = (const float*)d_in[9];
  float* out = (float*)d_out;

  // workspace layout (bytes), total ~96.8 MB:
  //   w1f fp16:   [0, 405504)
  //   w2f fp16:   [405504, 423936)
  //   w3f fp16:   [423936, 442368)
  //   wtg fp16:   [442368, 14893056)
  //   descF fp16: [14893056, 67878912)
  //   pacc fp16:  [67878912, 94371840)   (11 split-K slices)
  //   yred fp16:  [94371840, 96780288)
  _Float16* w1f = (_Float16*)d_ws;
  _Float16* w2f = w1f + 202752;
  _Float16* w3f = w2f + 9216;
  _Float16* wtg = (_Float16*)((char*)d_ws + 442368);
  _Float16* descF = (_Float16*)((char*)d_ws + 14893056);
  _Float16* pacc = (_Float16*)((char*)d_ws + 67878912);
  _Float16* yred = (_Float16*)((char*)d_ws + 94371840);

  hipLaunchKernelGGL(kW, dim3(864), dim3(256), 0, stream, w1, w2, w3, w1f, w2f, w3f);
  hipLaunchKernelGGL(kDesc, dim3(3584), dim3(320), 0, stream, x, descF);
  hipLaunchKernelGGL(kGemm1, dim3(2156), dim3(256), 0, stream, descF, w1f, pacc);
  hipLaunchKernelGGL(kRed, dim3(1176), dim3(256), 0, stream,
                     pacc, gamma, beta, mean, var, yred);
  hipLaunchKernelGGL(kGemm2, dim3(196), dim3(256), 0, stream,
                     yred, w2f, w3f, b2, b3, wtg);
  hipLaunchKernelGGL(kApply, dim3(7168), dim3(256), 0, stream, x, wtg, out);
}